// Round 2
// baseline (191.275 us; speedup 1.0000x reference)
//
#include <hip/hip_runtime.h>

typedef __attribute__((ext_vector_type(8))) short bf16x8;
typedef __attribute__((ext_vector_type(4))) float f32x4;
typedef __attribute__((ext_vector_type(4))) unsigned short u16x4;

__device__ __forceinline__ unsigned short f2bf_rne(float f) {
  unsigned u = __float_as_uint(f);
  u += 0x7FFFu + ((u >> 16) & 1u);
  return (unsigned short)(u >> 16);
}
__device__ __forceinline__ float bf2f(unsigned short h) {
  return __uint_as_float(((unsigned)h) << 16);
}
__device__ __forceinline__ unsigned umin2(unsigned a, unsigned b) { return a < b ? a : b; }

// ---------------- Kernel 1: prep ----------------
// codebook fp32 -> bf16 (ws), norms = sum(bf16(e)^2) (consistent with MFMA dot),
// zero the loss accumulator at d_out[N*D].
__global__ void vq_prep(const float* __restrict__ cb,
                        float* __restrict__ norms,
                        unsigned short* __restrict__ cbh,
                        float* __restrict__ loss_out) {
  if (blockIdx.x == 0 && threadIdx.x == 0) *loss_out = 0.0f;
  const int lane = threadIdx.x & 63;
  const int code = (blockIdx.x * blockDim.x + threadIdx.x) >> 6;  // one wave per code
  const f32x4 v = ((const f32x4*)(cb + (long)code * 256))[lane];
  u16x4 h;
  float n = 0.f;
#pragma unroll
  for (int j = 0; j < 4; ++j) {
    unsigned short b = f2bf_rne(v[j]);
    h[j] = (unsigned short)b;
    float bf = bf2f(b);
    n += bf * bf;
  }
  ((u16x4*)(cbh + (long)code * 256))[lane] = h;
#pragma unroll
  for (int m = 1; m < 64; m <<= 1) n += __shfl_xor(n, m);
  if (lane == 0) norms[code] = n;
}

// ---------------- Kernel 2: main ----------------
#define BM 128   // rows per block
#define DD 256   // embedding dim
#define NTHR 512

__global__ __launch_bounds__(NTHR, 4)
void vq_main(const float* __restrict__ X,
             const float* __restrict__ CB,
             const float* __restrict__ norms,
             const unsigned short* __restrict__ cbh,
             float* __restrict__ out,
             float* __restrict__ loss_out,
             float lscale) {
  __shared__ __attribute__((aligned(16))) unsigned short Xs[BM * DD];  // 64 KiB swizzled bf16
  __shared__ float wsum[8];

  const int t = threadIdx.x;
  const int lane = t & 63;
  const int wave = t >> 6;   // 0..7
  const int wr = wave >> 2;  // 0..1: row half (64 rows)
  const int wc = wave & 3;   // 0..3: code quarter (32 codes of 128-tile)
  const int lo16 = lane & 15;
  const int hi = lane >> 4;
  const long rowBase = (long)blockIdx.x * BM;

  // ---- stage X: fp32 global -> bf16 LDS, XOR-swizzled (byte ^= (row&7)<<4) ----
  {
    const f32x4* Xg = (const f32x4*)(X + rowBase * DD);
#pragma unroll
    for (int i = 0; i < 16; ++i) {
      int idx = t + NTHR * i;  // 8192 float4 chunks
      int row = idx >> 6, d4 = idx & 63;
      f32x4 v = Xg[idx];
      u16x4 h;
#pragma unroll
      for (int j = 0; j < 4; ++j) h[j] = f2bf_rne(v[j]);
      unsigned byte = (unsigned)(row * 512 + d4 * 8) ^ (unsigned)((row & 7) << 4);
      *(u16x4*)((char*)Xs + byte) = h;
    }
  }
  __syncthreads();

  // per-m LDS byte base (row*512 ^ swz); inner offset XORs in (ks*64 + hi*16)
  unsigned aoff[4];
#pragma unroll
  for (int m = 0; m < 4; ++m) {
    int row = wr * 64 + m * 16 + lo16;
    aoff[m] = (unsigned)(row * 512) ^ (unsigned)((row & 7) << 4);
  }
  const bf16x8* __restrict__ Bg = (const bf16x8*)cbh;  // 16B units; 32 per code row
  int bbase[2];
#pragma unroll
  for (int n = 0; n < 2; ++n) bbase[n] = (wc * 32 + n * 16 + lo16) * 32 + hi;

  unsigned best[4][4];
#pragma unroll
  for (int m = 0; m < 4; ++m)
#pragma unroll
    for (int r = 0; r < 4; ++r) best[m][r] = 0xFFFFFFFFu;

  for (int ct = 0; ct < 8; ++ct) {  // 8 code-tiles of 128; NO barriers inside
    float nrm[2];
#pragma unroll
    for (int n = 0; n < 2; ++n) nrm[n] = norms[ct * 128 + wc * 32 + n * 16 + lo16];

    f32x4 acc[4][2];
#pragma unroll
    for (int m = 0; m < 4; ++m)
#pragma unroll
      for (int n = 0; n < 2; ++n) {
        f32x4 z = {0.f, 0.f, 0.f, 0.f};
        acc[m][n] = z;
      }

#pragma unroll
    for (int ks = 0; ks < 8; ++ks) {
      bf16x8 b[2];
#pragma unroll
      for (int n = 0; n < 2; ++n) b[n] = Bg[(long)ct * 4096 + bbase[n] + ks * 4];
      bf16x8 a[4];
#pragma unroll
      for (int m = 0; m < 4; ++m) {
        unsigned byte = aoff[m] ^ (unsigned)(ks * 64 + hi * 16);
        a[m] = *(const bf16x8*)((const char*)Xs + byte);
      }
#pragma unroll
      for (int m = 0; m < 4; ++m)
#pragma unroll
        for (int n = 0; n < 2; ++n)
          acc[m][n] = __builtin_amdgcn_mfma_f32_16x16x32_bf16(a[m], b[n], acc[m][n], 0, 0, 0);
    }

    // score = ||e||^2 - 2 x.e; pack (monotone(score) & ~1023) | code; running min
#pragma unroll
    for (int m = 0; m < 4; ++m)
#pragma unroll
      for (int r = 0; r < 4; ++r) {
        unsigned e01 = 0xFFFFFFFFu;
#pragma unroll
        for (int n = 0; n < 2; ++n) {
          float s = __builtin_fmaf(-2.0f, acc[m][n][r], nrm[n]);
          unsigned u = __float_as_uint(s);
          u = ((int)u < 0) ? ~u : (u | 0x80000000u);
          unsigned enc = (u & 0xFFFFFC00u) | (unsigned)(ct * 128 + wc * 32 + n * 16 + lo16);
          e01 = umin2(e01, enc);
        }
        best[m][r] = umin2(best[m][r], e01);
      }
  }

  // ---- one butterfly over the 16 code-columns, then cross-wave merge ----
#pragma unroll
  for (int m = 0; m < 4; ++m)
#pragma unroll
    for (int r = 0; r < 4; ++r) {
#pragma unroll
      for (int msk = 1; msk < 16; msk <<= 1)
        best[m][r] = umin2(best[m][r], (unsigned)__shfl_xor((int)best[m][r], msk));
    }

  __syncthreads();  // all waves done reading Xs; reuse as merge buffer
  unsigned* mg = (unsigned*)Xs;  // [4][BM]
  if (lo16 == 0) {
#pragma unroll
    for (int m = 0; m < 4; ++m)
#pragma unroll
      for (int r = 0; r < 4; ++r) {
        int row = wr * 64 + m * 16 + hi * 4 + r;  // C/D layout: row=(lane>>4)*4+reg
        mg[wc * BM + row] = best[m][r];
      }
  }
  __syncthreads();
  unsigned* idxArr = mg + 4 * BM;
  if (t < BM) {
    unsigned e = umin2(umin2(mg[t], mg[BM + t]), umin2(mg[2 * BM + t], mg[3 * BM + t]));
    idxArr[t] = e & 1023u;
  }
  __syncthreads();

  // ---- gather fp32 codebook rows -> output; fp32 MSE partial ----
  float ls = 0.f;
  {
    const f32x4* Xg = (const f32x4*)(X + rowBase * DD);
    const f32x4* CBv = (const f32x4*)CB;
    f32x4* Og = (f32x4*)(out + rowBase * DD);
#pragma unroll 4
    for (int i = 0; i < 16; ++i) {
      int idx = t + NTHR * i;
      int row = idx >> 6, d4 = idx & 63;
      int code = (int)idxArr[row];
      f32x4 e = CBv[code * 64 + d4];
      f32x4 x = Xg[idx];
      Og[idx] = e;
#pragma unroll
      for (int j = 0; j < 4; ++j) {
        float df = e[j] - x[j];
        ls = __builtin_fmaf(df, df, ls);
      }
    }
  }
#pragma unroll
  for (int msk = 1; msk < 64; msk <<= 1) ls += __shfl_xor(ls, msk);
  if (lane == 0) wsum[wave] = ls;
  __syncthreads();
  if (t == 0) {
    float tot = 0.f;
#pragma unroll
    for (int w = 0; w < 8; ++w) tot += wsum[w];
    atomicAdd(loss_out, tot * lscale);
  }
}

extern "C" void kernel_launch(void* const* d_in, const int* in_sizes, int n_in,
                              void* d_out, int out_size, void* d_ws, size_t ws_size,
                              hipStream_t stream) {
  const float* X = (const float*)d_in[0];
  const float* CB = (const float*)d_in[1];
  float* out = (float*)d_out;

  const int ND = in_sizes[0];      // 16*4096*256 = 16777216
  const int K = in_sizes[1] / DD;  // 1024
  const int N = ND / DD;           // 65536

  float* ws_norms = (float*)d_ws;  // K floats
  unsigned short* ws_cb = (unsigned short*)((char*)d_ws + (size_t)K * sizeof(float));
  float* loss_out = out + (size_t)ND;

  vq_prep<<<K / 4, 256, 0, stream>>>(CB, ws_norms, ws_cb, loss_out);

  const float lscale = 1.25f / (float)ND;
  vq_main<<<N / BM, NTHR, 0, stream>>>(X, CB, ws_norms, ws_cb, out, loss_out, lscale);
}

// Round 4
// 191.188 us; speedup vs baseline: 1.0005x; 1.0005x over previous
//
#include <hip/hip_runtime.h>

typedef __attribute__((ext_vector_type(8))) short bf16x8;
typedef __attribute__((ext_vector_type(4))) float f32x4;
typedef __attribute__((ext_vector_type(4))) unsigned short u16x4;

__device__ __forceinline__ unsigned short f2bf_rne(float f) {
  unsigned u = __float_as_uint(f);
  u += 0x7FFFu + ((u >> 16) & 1u);
  return (unsigned short)(u >> 16);
}
__device__ __forceinline__ float bf2f(unsigned short h) {
  return __uint_as_float(((unsigned)h) << 16);
}
__device__ __forceinline__ unsigned umin2(unsigned a, unsigned b) { return a < b ? a : b; }

// ---------------- Kernel 1: prep ----------------
// codebook fp32 -> bf16 (ws), norms = sum(bf16(e)^2) (consistent with MFMA dot),
// zero the loss accumulator at d_out[N*D].
__global__ void vq_prep(const float* __restrict__ cb,
                        float* __restrict__ norms,
                        unsigned short* __restrict__ cbh,
                        float* __restrict__ loss_out) {
  if (blockIdx.x == 0 && threadIdx.x == 0) *loss_out = 0.0f;
  const int lane = threadIdx.x & 63;
  const int code = (blockIdx.x * blockDim.x + threadIdx.x) >> 6;  // one wave per code
  const f32x4 v = ((const f32x4*)(cb + (long)code * 256))[lane];
  u16x4 h;
  float n = 0.f;
#pragma unroll
  for (int j = 0; j < 4; ++j) {
    unsigned short b = f2bf_rne(v[j]);
    h[j] = (unsigned short)b;
    float bf = bf2f(b);
    n += bf * bf;
  }
  ((u16x4*)(cbh + (long)code * 256))[lane] = h;
#pragma unroll
  for (int m = 1; m < 64; m <<= 1) n += __shfl_xor(n, m);
  if (lane == 0) norms[code] = n;
}

// ---------------- Kernel 2: main ----------------
#define BM 128   // rows per block
#define DD 256   // embedding dim
#define NTHR 512

__global__ __launch_bounds__(NTHR, 4)
void vq_main(const float* __restrict__ X,
             const float* __restrict__ CB,
             const float* __restrict__ norms,
             const unsigned short* __restrict__ cbh,
             float* __restrict__ out,
             float* __restrict__ loss_out,
             float lscale) {
  __shared__ __attribute__((aligned(16))) unsigned short Xs[BM * DD];  // 64 KiB swizzled bf16
  __shared__ float wsumX[8];
  __shared__ float wsumS[8];

  const int t = threadIdx.x;
  const int lane = t & 63;
  const int wave = t >> 6;   // 0..7
  const int wr = wave >> 2;  // 0..1: row half (64 rows)
  const int wc = wave & 3;   // 0..3: code quarter (32 codes of 128-tile)
  const int lo16 = lane & 15;
  const int hi = lane >> 4;
  const long rowBase = (long)blockIdx.x * BM;

  // ---- stage X: fp32 global (non-temporal) -> bf16 LDS, XOR-swizzled; accumulate ||x||^2 ----
  float xn = 0.f;
  {
    const f32x4* Xg = (const f32x4*)(X + rowBase * DD);
#pragma unroll
    for (int i = 0; i < 16; ++i) {
      int idx = t + NTHR * i;  // 8192 float4 chunks
      int row = idx >> 6, d4 = idx & 63;
      f32x4 v = __builtin_nontemporal_load(Xg + idx);
      u16x4 h;
#pragma unroll
      for (int j = 0; j < 4; ++j) {
        xn = __builtin_fmaf(v[j], v[j], xn);
        h[j] = f2bf_rne(v[j]);
      }
      unsigned byte = (unsigned)(row * 512 + d4 * 8) ^ (unsigned)((row & 7) << 4);
      *(u16x4*)((char*)Xs + byte) = h;
    }
  }
#pragma unroll
  for (int msk = 1; msk < 64; msk <<= 1) xn += __shfl_xor(xn, msk);
  if (lane == 0) wsumX[wave] = xn;
  __syncthreads();

  // per-m LDS byte base (row*512 ^ swz).  NOTE: the k-offset (ks*64+hi*16, bits 4-8)
  // OVERLAPS the swizzle bits 4-6, so it must be composed with XOR, never ADD:
  // (row*512 ^ swz) ^ koff == (row*512 + koff) ^ swz  because row*512 lives in bits >=9.
  unsigned aoff[4];
#pragma unroll
  for (int m = 0; m < 4; ++m) {
    int row = wr * 64 + m * 16 + lo16;
    aoff[m] = (unsigned)(row * 512) ^ (unsigned)((row & 7) << 4);
  }
  const bf16x8* __restrict__ Bg = (const bf16x8*)cbh;  // 16B units; 32 per code row
  int bbase[2];
#pragma unroll
  for (int n = 0; n < 2; ++n) bbase[n] = (wc * 32 + n * 16 + lo16) * 32 + hi;

  // depth-4 rotating B prefetch buffer (2 k-steps ahead, crosses ct boundaries)
  bf16x8 bbuf[4][2];
#pragma unroll
  for (int f = 0; f < 2; ++f)
#pragma unroll
    for (int n = 0; n < 2; ++n) bbuf[f][n] = Bg[bbase[n] + f * 4];

  unsigned best[4][4];
#pragma unroll
  for (int m = 0; m < 4; ++m)
#pragma unroll
    for (int r = 0; r < 4; ++r) best[m][r] = 0xFFFFFFFFu;

  for (int ct = 0; ct < 8; ++ct) {  // 8 code-tiles of 128; NO barriers inside
    float nrm[2];
#pragma unroll
    for (int n = 0; n < 2; ++n) nrm[n] = norms[ct * 128 + wc * 32 + n * 16 + lo16];

    f32x4 acc[4][2];
#pragma unroll
    for (int m = 0; m < 4; ++m)
#pragma unroll
      for (int n = 0; n < 2; ++n) {
        f32x4 z = {0.f, 0.f, 0.f, 0.f};
        acc[m][n] = z;
      }

#pragma unroll
    for (int ks = 0; ks < 8; ++ks) {
      const int f = ct * 8 + ks + 2;  // flat prefetch index, 2 ahead
      if (f < 64) {
        const long off = (long)(f >> 3) * 4096 + (f & 7) * 4;
#pragma unroll
        for (int n = 0; n < 2; ++n) bbuf[(ks + 2) & 3][n] = Bg[off + bbase[n]];
      }
      bf16x8 a[4];
#pragma unroll
      for (int m = 0; m < 4; ++m) {
        unsigned byte = aoff[m] ^ (unsigned)(ks * 64 + hi * 16);  // XOR, not ADD (see note)
        a[m] = *(const bf16x8*)((const char*)Xs + byte);
      }
#pragma unroll
      for (int m = 0; m < 4; ++m)
#pragma unroll
        for (int n = 0; n < 2; ++n)
          acc[m][n] = __builtin_amdgcn_mfma_f32_16x16x32_bf16(a[m], bbuf[ks & 3][n], acc[m][n], 0, 0, 0);
    }

    // score = ||e||^2 - 2 x.e; pack (monotone(score) & ~1023) | code; running min
#pragma unroll
    for (int m = 0; m < 4; ++m)
#pragma unroll
      for (int r = 0; r < 4; ++r) {
        unsigned e01 = 0xFFFFFFFFu;
#pragma unroll
        for (int n = 0; n < 2; ++n) {
          float s = __builtin_fmaf(-2.0f, acc[m][n][r], nrm[n]);
          unsigned u = __float_as_uint(s);
          u = ((int)u < 0) ? ~u : (u | 0x80000000u);
          unsigned enc = (u & 0xFFFFFC00u) | (unsigned)(ct * 128 + wc * 32 + n * 16 + lo16);
          e01 = umin2(e01, enc);
        }
        best[m][r] = umin2(best[m][r], e01);
      }
  }

  // ---- one butterfly over the 16 code-columns, then cross-wave merge ----
#pragma unroll
  for (int m = 0; m < 4; ++m)
#pragma unroll
    for (int r = 0; r < 4; ++r) {
#pragma unroll
      for (int msk = 1; msk < 16; msk <<= 1)
        best[m][r] = umin2(best[m][r], (unsigned)__shfl_xor((int)best[m][r], msk));
    }

  __syncthreads();  // all waves done reading Xs; reuse as merge buffer
  unsigned* mg = (unsigned*)Xs;  // [4][BM]
  if (lo16 == 0) {
#pragma unroll
    for (int m = 0; m < 4; ++m)
#pragma unroll
      for (int r = 0; r < 4; ++r) {
        int row = wr * 64 + m * 16 + hi * 4 + r;  // C/D layout: row=(lane>>4)*4+reg
        mg[wc * BM + row] = best[m][r];
      }
  }
  __syncthreads();
  unsigned* idxArr = mg + 4 * BM;
  float sc = 0.f;
  if (t < BM) {
    unsigned e = umin2(umin2(mg[t], mg[BM + t]), umin2(mg[2 * BM + t], mg[3 * BM + t]));
    idxArr[t] = e & 1023u;
    // decode score (midpoint of truncated key) for the analytic loss
    unsigned um = (e & 0xFFFFFC00u) | 512u;
    sc = (um & 0x80000000u) ? __uint_as_float(um & 0x7FFFFFFFu) : __uint_as_float(~um);
  }
#pragma unroll
  for (int msk = 1; msk < 64; msk <<= 1) sc += __shfl_xor(sc, msk);
  if (lane == 0) wsumS[wave] = sc;
  __syncthreads();

  // ---- gather fp32 codebook rows -> output (non-temporal store) ----
  {
    const f32x4* CBv = (const f32x4*)CB;
    f32x4* Og = (f32x4*)(out + rowBase * DD);
#pragma unroll 4
    for (int i = 0; i < 16; ++i) {
      int idx = t + NTHR * i;
      int row = idx >> 6, d4 = idx & 63;
      int code = (int)idxArr[row];
      f32x4 e = CBv[code * 64 + d4];
      __builtin_nontemporal_store(e, Og + idx);
    }
  }

  if (t == 0) {
    float tot = 0.f;
#pragma unroll
    for (int w = 0; w < 8; ++w) tot += wsumX[w] + wsumS[w];
    atomicAdd(loss_out, tot * lscale);
  }
}

extern "C" void kernel_launch(void* const* d_in, const int* in_sizes, int n_in,
                              void* d_out, int out_size, void* d_ws, size_t ws_size,
                              hipStream_t stream) {
  const float* X = (const float*)d_in[0];
  const float* CB = (const float*)d_in[1];
  float* out = (float*)d_out;

  const int ND = in_sizes[0];      // 16*4096*256 = 16777216
  const int K = in_sizes[1] / DD;  // 1024
  const int N = ND / DD;           // 65536

  float* ws_norms = (float*)d_ws;  // K floats
  unsigned short* ws_cb = (unsigned short*)((char*)d_ws + (size_t)K * sizeof(float));
  float* loss_out = out + (size_t)ND;

  vq_prep<<<K / 4, 256, 0, stream>>>(CB, ws_norms, ws_cb, loss_out);

  const float lscale = 1.25f / (float)ND;
  vq_main<<<N / BM, NTHR, 0, stream>>>(X, CB, ws_norms, ws_cb, out, loss_out, lscale);
}

// Round 5
// 73.416 us; speedup vs baseline: 2.6054x; 2.6042x over previous
//
#include <hip/hip_runtime.h>

typedef __attribute__((ext_vector_type(8))) short bf16x8;
typedef __attribute__((ext_vector_type(4))) float f32x4;
typedef __attribute__((ext_vector_type(4))) unsigned short u16x4;

static __device__ __forceinline__ unsigned short f2bf_rne(float f) {
  unsigned u = __float_as_uint(f);
  u += 0x7FFFu + ((u >> 16) & 1u);
  return (unsigned short)(u >> 16);
}
static __device__ __forceinline__ float bf2f(unsigned short h) {
  return __uint_as_float(((unsigned)h) << 16);
}
static __device__ __forceinline__ unsigned umin2(unsigned a, unsigned b) { return a < b ? a : b; }

// ---------------- Kernel 1: prep ----------------
// codebook fp32 -> bf16 (ws), nrmh = bf16(sum(bf16(e)^2)) (consistent with MFMA dot),
// zero the loss accumulator at d_out[N*D].
__global__ void vq_prep(const float* __restrict__ cb,
                        unsigned short* __restrict__ nrmh,
                        unsigned short* __restrict__ cbh,
                        float* __restrict__ loss_out) {
  if (blockIdx.x == 0 && threadIdx.x == 0) *loss_out = 0.0f;
  const int lane = threadIdx.x & 63;
  const int code = (blockIdx.x * blockDim.x + threadIdx.x) >> 6;  // one wave per code
  const f32x4 v = ((const f32x4*)(cb + (long)code * 256))[lane];
  u16x4 h;
  float n = 0.f;
#pragma unroll
  for (int j = 0; j < 4; ++j) {
    unsigned short b = f2bf_rne(v[j]);
    h[j] = (unsigned short)b;
    float bf = bf2f(b);
    n = __builtin_fmaf(bf, bf, n);
  }
  ((u16x4*)(cbh + (long)code * 256))[lane] = h;
#pragma unroll
  for (int m = 1; m < 64; m <<= 1) n += __shfl_xor(n, m);
  if (lane == 0) nrmh[code] = f2bf_rne(n);
}

// ---------------- Kernel 2: main ----------------
#define BM 128    // rows per block
#define DD 256    // embedding dim
#define NTHR 512  // 8 waves
#define CT 32     // codes per subtile (16 KiB bf16)
#define NSUB 32   // 1024 / CT

__global__ __launch_bounds__(NTHR, 4)
void vq_main(const float* __restrict__ X,
             const float* __restrict__ CB,
             const unsigned short* __restrict__ nrmh_g,
             const unsigned short* __restrict__ cbh,
             float* __restrict__ out,
             float* __restrict__ loss_out,
             float lscale) {
  // E double buffer: 2 x (32 codes x 256 dims) bf16 = 32 KiB, swizzled
  __shared__ __attribute__((aligned(16))) unsigned short Eb[2 * CT * DD];
  __shared__ __attribute__((aligned(16))) unsigned short nrmLds[1024];  // 2 KiB
  __shared__ float wsumX[8];
  __shared__ float wsumS[8];

  const int t = threadIdx.x;
  const int lane = t & 63;
  const int wave = t >> 6;  // 0..7 : owns rows 16*wave .. 16*wave+15
  const int lo16 = lane & 15;
  const int hi = lane >> 4;
  const long rowBase = (long)blockIdx.x * BM;

  // ---- stage all 1024 bf16 norms into LDS ----
  ((unsigned*)nrmLds)[t] = ((const unsigned*)nrmh_g)[t];  // 512 x 4B = 2 KiB

  // ---- A preload: 16 rows/wave, fp32 global (nt) -> bf16 regs; accumulate ||x||^2 ----
  float xn = 0.f;
  bf16x8 a[8];
  {
    const f32x4* xr = (const f32x4*)(X + (rowBase + wave * 16 + lo16) * DD);
#pragma unroll
    for (int ks = 0; ks < 8; ++ks) {
      f32x4 v0 = __builtin_nontemporal_load(xr + ks * 8 + hi * 2);
      f32x4 v1 = __builtin_nontemporal_load(xr + ks * 8 + hi * 2 + 1);
      bf16x8 aa;
#pragma unroll
      for (int j = 0; j < 4; ++j) {
        xn = __builtin_fmaf(v0[j], v0[j], xn);
        aa[j] = (short)f2bf_rne(v0[j]);
      }
#pragma unroll
      for (int j = 0; j < 4; ++j) {
        xn = __builtin_fmaf(v1[j], v1[j], xn);
        aa[4 + j] = (short)f2bf_rne(v1[j]);
      }
      a[ks] = aa;
    }
  }
  __syncthreads();  // nrmLds visible to all

  // ---- stage(0): subtile 0 -> buf 0.  Per wave: 2 global_load_lds of 16B/lane.
  // LDS dest is linear (wave-uniform base + lane*16); global SOURCE is pre-swizzled
  // with the involution  o ^= ((o>>9)&7)<<4  so that swizzled ds_reads decode it.
  const char* cbB = (const char*)cbh;
  char* ebBase = (char*)Eb;
#define STAGE_E(ST, BUF)                                                              \
  {                                                                                   \
    _Pragma("unroll") for (int c = 0; c < 2; ++c) {                                   \
      unsigned o = (unsigned)(c * 8192 + wave * 1024 + lane * 16);                    \
      unsigned src = o ^ (((o >> 9) & 7u) << 4);                                      \
      __builtin_amdgcn_global_load_lds(                                               \
          (const __attribute__((address_space(1))) void*)(cbB + (unsigned)(ST)*16384u + src), \
          (__attribute__((address_space(3))) void*)(ebBase + (BUF)*16384 + c * 8192 + wave * 1024), \
          16, 0, 0);                                                                  \
    }                                                                                 \
  }

  STAGE_E(0, 0);

  unsigned best[4];
#pragma unroll
  for (int r = 0; r < 4; ++r) best[r] = 0xFFFFFFFFu;

  const unsigned swzl = (unsigned)((lo16 & 7) << 4);
  const unsigned hi16 = (unsigned)(hi * 16);
  const unsigned base0 = (unsigned)(lo16 * 512);
  const unsigned base1 = base0 + 16u * 512u;

#pragma unroll 2
  for (int st = 0; st < NSUB; ++st) {
    if (st + 1 < NSUB) {
      STAGE_E(st + 1, (st + 1) & 1);
      asm volatile("s_waitcnt vmcnt(2)" ::: "memory");  // subtile st's 2 chunks landed; st+1 in flight
    } else {
      asm volatile("s_waitcnt vmcnt(0)" ::: "memory");
    }
    __builtin_amdgcn_s_barrier();          // all waves' stage(st) writes visible
    __builtin_amdgcn_sched_barrier(0);     // pin: no ds_read hoists above (rule #18)

    const char* eb = ebBase + (st & 1) * 16384;
    f32x4 acc0 = {0.f, 0.f, 0.f, 0.f};
    f32x4 acc1 = {0.f, 0.f, 0.f, 0.f};
#pragma unroll
    for (int ks = 0; ks < 8; ++ks) {
      unsigned kx = ((unsigned)(ks * 64) + hi16) ^ swzl;  // XOR-compose swizzle (bits 4-6 overlap)
      bf16x8 b0 = *(const bf16x8*)(eb + base0 + kx);
      bf16x8 b1 = *(const bf16x8*)(eb + base1 + kx);
      acc0 = __builtin_amdgcn_mfma_f32_16x16x32_bf16(a[ks], b0, acc0, 0, 0, 0);
      acc1 = __builtin_amdgcn_mfma_f32_16x16x32_bf16(a[ks], b1, acc1, 0, 0, 0);
    }

    // score = ||e||^2 - 2 x.e; pack (monotone(score) & ~1023) | code; running min
    float nf0 = bf2f(nrmLds[st * 32 + lo16]);
    float nf1 = bf2f(nrmLds[st * 32 + 16 + lo16]);
#pragma unroll
    for (int r = 0; r < 4; ++r) {
      float s0 = __builtin_fmaf(-2.0f, acc0[r], nf0);
      unsigned u0 = __float_as_uint(s0);
      u0 = ((int)u0 < 0) ? ~u0 : (u0 | 0x80000000u);
      unsigned e0 = (u0 & 0xFFFFFC00u) | (unsigned)(st * 32 + lo16);
      float s1 = __builtin_fmaf(-2.0f, acc1[r], nf1);
      unsigned u1 = __float_as_uint(s1);
      u1 = ((int)u1 < 0) ? ~u1 : (u1 | 0x80000000u);
      unsigned e1 = (u1 & 0xFFFFFC00u) | (unsigned)(st * 32 + 16 + lo16);
      best[r] = umin2(best[r], umin2(e0, e1));
    }

    __builtin_amdgcn_sched_barrier(0);     // keep this subtile's reads/MFMA above barrier B
    __builtin_amdgcn_s_barrier();          // slot st&1 free for stage(st+2)
  }

  // ---- butterfly over the 16 code-lanes: per-row global min ----
#pragma unroll
  for (int r = 0; r < 4; ++r) {
#pragma unroll
    for (int msk = 1; msk < 16; msk <<= 1)
      best[r] = umin2(best[r], (unsigned)__shfl_xor((int)best[r], msk));
  }

  // ---- wave-reduce ||x||^2 partials ----
#pragma unroll
  for (int msk = 1; msk < 64; msk <<= 1) xn += __shfl_xor(xn, msk);
  if (lane == 0) wsumX[wave] = xn;

  __syncthreads();  // Eb free; all vmcnt drained (last iter waited vmcnt(0))
  unsigned* mg = (unsigned*)Eb;     // [128] final keys
  unsigned* idxArr = mg + BM;       // [128] decoded indices
  if (lo16 == 0) {
#pragma unroll
    for (int r = 0; r < 4; ++r) {
      // C/D layout: row_in_16 = (lane>>4)*4 + r
      mg[wave * 16 + hi * 4 + r] = best[r];
    }
  }
  __syncthreads();
  float sc = 0.f;
  if (t < BM) {
    unsigned e = mg[t];
    idxArr[t] = e & 1023u;
    // decode score (midpoint of truncated key) for the analytic loss
    unsigned um = (e & 0xFFFFFC00u) | 512u;
    sc = (um & 0x80000000u) ? __uint_as_float(um & 0x7FFFFFFFu) : __uint_as_float(~um);
  }
#pragma unroll
  for (int msk = 1; msk < 64; msk <<= 1) sc += __shfl_xor(sc, msk);
  if (lane == 0) wsumS[wave] = sc;
  __syncthreads();

  // ---- gather fp32 codebook rows -> output (non-temporal store) ----
  {
    const f32x4* CBv = (const f32x4*)CB;
    f32x4* Og = (f32x4*)(out + rowBase * DD);
#pragma unroll 4
    for (int i = 0; i < 16; ++i) {
      int idx = t + NTHR * i;
      int row = idx >> 6, d4 = idx & 63;
      int code = (int)idxArr[row];
      f32x4 e = CBv[code * 64 + d4];
      __builtin_nontemporal_store(e, Og + idx);
    }
  }

  if (t == 0) {
    float tot = 0.f;
#pragma unroll
    for (int w = 0; w < 8; ++w) tot += wsumX[w] + wsumS[w];
    atomicAdd(loss_out, tot * lscale);
  }
}

extern "C" void kernel_launch(void* const* d_in, const int* in_sizes, int n_in,
                              void* d_out, int out_size, void* d_ws, size_t ws_size,
                              hipStream_t stream) {
  const float* X = (const float*)d_in[0];
  const float* CB = (const float*)d_in[1];
  float* out = (float*)d_out;

  const int ND = in_sizes[0];      // 16*4096*256 = 16777216
  const int K = in_sizes[1] / DD;  // 1024
  const int N = ND / DD;           // 65536

  unsigned short* ws_nrmh = (unsigned short*)d_ws;                    // K bf16 (2 KiB)
  unsigned short* ws_cb = (unsigned short*)((char*)d_ws + 2048);      // K*D bf16
  float* loss_out = out + (size_t)ND;

  vq_prep<<<K / 4, 256, 0, stream>>>(CB, ws_nrmh, ws_cb, loss_out);

  const float lscale = 1.25f / (float)ND;
  vq_main<<<N / BM, NTHR, 0, stream>>>(X, CB, ws_nrmh, ws_cb, out, loss_out, lscale);
}

// Round 6
// 66.495 us; speedup vs baseline: 2.8765x; 1.1041x over previous
//
#include <hip/hip_runtime.h>

typedef __attribute__((ext_vector_type(8))) short bf16x8;
typedef __attribute__((ext_vector_type(4))) float f32x4;
typedef __attribute__((ext_vector_type(4))) unsigned short u16x4;

static __device__ __forceinline__ unsigned short f2bf_rne(float f) {
  unsigned u = __float_as_uint(f);
  u += 0x7FFFu + ((u >> 16) & 1u);
  return (unsigned short)(u >> 16);
}
static __device__ __forceinline__ float bf2f(unsigned short h) {
  return __uint_as_float(((unsigned)h) << 16);
}
static __device__ __forceinline__ unsigned umin2(unsigned a, unsigned b) { return a < b ? a : b; }

// ---------------- Kernel 1: prep ----------------
// codebook fp32 -> bf16 (ws), nrmh = bf16(sum(bf16(e)^2)) (consistent with MFMA dot),
// zero the loss accumulator at d_out[N*D].
__global__ void vq_prep(const float* __restrict__ cb,
                        unsigned short* __restrict__ nrmh,
                        unsigned short* __restrict__ cbh,
                        float* __restrict__ loss_out) {
  if (blockIdx.x == 0 && threadIdx.x == 0) *loss_out = 0.0f;
  const int lane = threadIdx.x & 63;
  const int code = (blockIdx.x * blockDim.x + threadIdx.x) >> 6;  // one wave per code
  const f32x4 v = ((const f32x4*)(cb + (long)code * 256))[lane];
  u16x4 h;
  float n = 0.f;
#pragma unroll
  for (int j = 0; j < 4; ++j) {
    unsigned short b = f2bf_rne(v[j]);
    h[j] = (unsigned short)b;
    float bf = bf2f(b);
    n = __builtin_fmaf(bf, bf, n);
  }
  ((u16x4*)(cbh + (long)code * 256))[lane] = h;
#pragma unroll
  for (int m = 1; m < 64; m <<= 1) n += __shfl_xor(n, m);
  if (lane == 0) nrmh[code] = f2bf_rne(n);
}

// ---------------- Kernel 2: main ----------------
#define BM 128    // rows per block
#define DD 256    // embedding dim
#define NTHR 256  // 4 waves, 32 rows per wave (M_w=32)
#define CT 32     // codes per subtile (16 KiB bf16)
#define NSUB 32   // 1024 / CT

__global__ __launch_bounds__(NTHR, 2)
void vq_main(const float* __restrict__ X,
             const float* __restrict__ CB,
             const unsigned short* __restrict__ nrmh_g,
             const unsigned short* __restrict__ cbh,
             float* __restrict__ out,
             float* __restrict__ loss_out,
             float lscale) {
  // E double buffer: 2 x (32 codes x 256 dims) bf16 = 32 KiB, swizzled
  __shared__ __attribute__((aligned(16))) unsigned short Eb[2 * CT * DD];
  __shared__ __attribute__((aligned(16))) unsigned short nrmLds[1024];  // 2 KiB
  __shared__ float wsumX[4];
  __shared__ float wsumS[4];

  const int t = threadIdx.x;
  const int lane = t & 63;
  const int wave = t >> 6;  // 0..3 : owns rows 32*wave .. 32*wave+31
  const int lo16 = lane & 15;
  const int hi = lane >> 4;
  const long rowBase = (long)blockIdx.x * BM;

  // ---- stage all 1024 bf16 norms into LDS (512 u32 by 256 threads) ----
  ((unsigned*)nrmLds)[t] = ((const unsigned*)nrmh_g)[t];
  ((unsigned*)nrmLds)[t + 256] = ((const unsigned*)nrmh_g)[t + 256];

  // ---- A preload: 32 rows/wave (2 sets of 16), fp32 global (nt) -> bf16 regs; ||x||^2 ----
  float xn = 0.f;
  bf16x8 a[2][8];
#pragma unroll
  for (int s = 0; s < 2; ++s) {
    const f32x4* xr = (const f32x4*)(X + (rowBase + wave * 32 + s * 16 + lo16) * DD);
#pragma unroll
    for (int ks = 0; ks < 8; ++ks) {
      f32x4 v0 = __builtin_nontemporal_load(xr + ks * 8 + hi * 2);
      f32x4 v1 = __builtin_nontemporal_load(xr + ks * 8 + hi * 2 + 1);
      bf16x8 aa;
#pragma unroll
      for (int j = 0; j < 4; ++j) {
        xn = __builtin_fmaf(v0[j], v0[j], xn);
        aa[j] = (short)f2bf_rne(v0[j]);
      }
#pragma unroll
      for (int j = 0; j < 4; ++j) {
        xn = __builtin_fmaf(v1[j], v1[j], xn);
        aa[4 + j] = (short)f2bf_rne(v1[j]);
      }
      a[s][ks] = aa;
    }
  }
  __syncthreads();  // nrmLds visible to all

  // ---- staging: subtile = 16 KiB; 4 waves x 4 chunks x (64 lanes x 16B).
  // LDS dest linear (wave-uniform base + lane*16); global SOURCE pre-swizzled with the
  // involution o ^= ((o>>9)&7)<<4 so swizzled ds_reads decode it (rule #21).
  const char* cbB = (const char*)cbh;
  char* ebBase = (char*)Eb;
#define STAGE_E(ST, BUF)                                                                      \
  {                                                                                           \
    _Pragma("unroll") for (int c = 0; c < 4; ++c) {                                           \
      unsigned o = (unsigned)(wave * 4096 + c * 1024 + lane * 16);                            \
      unsigned src = o ^ (((o >> 9) & 7u) << 4);                                              \
      __builtin_amdgcn_global_load_lds(                                                       \
          (const __attribute__((address_space(1))) void*)(cbB + (unsigned)(ST)*16384u + src), \
          (__attribute__((address_space(3))) void*)(ebBase + (BUF)*16384 + wave * 4096 + c * 1024), \
          16, 0, 0);                                                                          \
    }                                                                                         \
  }

  STAGE_E(0, 0);

  unsigned best[2][4];
#pragma unroll
  for (int s = 0; s < 2; ++s)
#pragma unroll
    for (int r = 0; r < 4; ++r) best[s][r] = 0xFFFFFFFFu;

  const unsigned swzl = (unsigned)((lo16 & 7) << 4);
  const unsigned hi16 = (unsigned)(hi * 16);
  const unsigned base0 = (unsigned)(lo16 * 512);
  const unsigned base1 = base0 + 16u * 512u;

#pragma unroll 2
  for (int st = 0; st < NSUB; ++st) {
    if (st + 1 < NSUB) {
      STAGE_E(st + 1, (st + 1) & 1);
      asm volatile("s_waitcnt vmcnt(4)" ::: "memory");  // subtile st's 4 chunks landed; st+1 in flight
    } else {
      asm volatile("s_waitcnt vmcnt(0)" ::: "memory");
    }
    __builtin_amdgcn_s_barrier();       // all waves' stage(st) writes visible
    __builtin_amdgcn_sched_barrier(0);  // pin: no ds_read hoists above (rule #18)

    const char* eb = ebBase + (st & 1) * 16384;
    f32x4 acc[2][2];
#pragma unroll
    for (int s = 0; s < 2; ++s)
#pragma unroll
      for (int n = 0; n < 2; ++n) {
        f32x4 z = {0.f, 0.f, 0.f, 0.f};
        acc[s][n] = z;
      }
#pragma unroll
    for (int ks = 0; ks < 8; ++ks) {
      unsigned kx = ((unsigned)(ks * 64) + hi16) ^ swzl;  // XOR-compose swizzle (bits 4-6 overlap)
      bf16x8 b0 = *(const bf16x8*)(eb + base0 + kx);
      bf16x8 b1 = *(const bf16x8*)(eb + base1 + kx);
      acc[0][0] = __builtin_amdgcn_mfma_f32_16x16x32_bf16(a[0][ks], b0, acc[0][0], 0, 0, 0);
      acc[0][1] = __builtin_amdgcn_mfma_f32_16x16x32_bf16(a[0][ks], b1, acc[0][1], 0, 0, 0);
      acc[1][0] = __builtin_amdgcn_mfma_f32_16x16x32_bf16(a[1][ks], b0, acc[1][0], 0, 0, 0);
      acc[1][1] = __builtin_amdgcn_mfma_f32_16x16x32_bf16(a[1][ks], b1, acc[1][1], 0, 0, 0);
    }

    // score = ||e||^2 - 2 x.e; pack (monotone(score) & ~1023) | code; running min
    float nf0 = bf2f(nrmLds[st * 32 + lo16]);
    float nf1 = bf2f(nrmLds[st * 32 + 16 + lo16]);
#pragma unroll
    for (int s = 0; s < 2; ++s)
#pragma unroll
      for (int r = 0; r < 4; ++r) {
        float s0 = __builtin_fmaf(-2.0f, acc[s][0][r], nf0);
        unsigned u0 = __float_as_uint(s0);
        u0 = ((int)u0 < 0) ? ~u0 : (u0 | 0x80000000u);
        unsigned e0 = (u0 & 0xFFFFFC00u) | (unsigned)(st * 32 + lo16);
        float s1 = __builtin_fmaf(-2.0f, acc[s][1][r], nf1);
        unsigned u1 = __float_as_uint(s1);
        u1 = ((int)u1 < 0) ? ~u1 : (u1 | 0x80000000u);
        unsigned e1 = (u1 & 0xFFFFFC00u) | (unsigned)(st * 32 + 16 + lo16);
        best[s][r] = umin2(best[s][r], umin2(e0, e1));
      }

    __builtin_amdgcn_sched_barrier(0);  // keep this subtile's reads/MFMA above barrier B
    __builtin_amdgcn_s_barrier();       // slot st&1 free for stage(st+2)
  }

  // ---- butterfly over the 16 code-lanes: per-row global min ----
#pragma unroll
  for (int s = 0; s < 2; ++s)
#pragma unroll
    for (int r = 0; r < 4; ++r) {
#pragma unroll
      for (int msk = 1; msk < 16; msk <<= 1)
        best[s][r] = umin2(best[s][r], (unsigned)__shfl_xor((int)best[s][r], msk));
    }

  // ---- wave-reduce ||x||^2 partials ----
#pragma unroll
  for (int msk = 1; msk < 64; msk <<= 1) xn += __shfl_xor(xn, msk);
  if (lane == 0) wsumX[wave] = xn;

  __syncthreads();  // Eb free; all vmcnt drained (last iter waited vmcnt(0))
  unsigned* mg = (unsigned*)Eb;  // [128] final keys
  unsigned* idxArr = mg + BM;    // [128] decoded indices
  if (lo16 == 0) {
#pragma unroll
    for (int s = 0; s < 2; ++s)
#pragma unroll
      for (int r = 0; r < 4; ++r) {
        // C/D layout: row_in_16 = (lane>>4)*4 + r
        mg[wave * 32 + s * 16 + hi * 4 + r] = best[s][r];
      }
  }
  __syncthreads();
  float sc = 0.f;
  if (t < BM) {
    unsigned e = mg[t];
    idxArr[t] = e & 1023u;
    // decode score (midpoint of truncated key) for the analytic loss
    unsigned um = (e & 0xFFFFFC00u) | 512u;
    sc = (um & 0x80000000u) ? __uint_as_float(um & 0x7FFFFFFFu) : __uint_as_float(~um);
  }
#pragma unroll
  for (int msk = 1; msk < 64; msk <<= 1) sc += __shfl_xor(sc, msk);
  if (lane == 0) wsumS[wave] = sc;
  __syncthreads();

  // ---- gather fp32 codebook rows -> output (non-temporal store) ----
  {
    const f32x4* CBv = (const f32x4*)CB;
    f32x4* Og = (f32x4*)(out + rowBase * DD);
#pragma unroll 4
    for (int i = 0; i < 32; ++i) {
      int idx = t + NTHR * i;
      int row = idx >> 6, d4 = idx & 63;
      int code = (int)idxArr[row];
      f32x4 e = CBv[code * 64 + d4];
      __builtin_nontemporal_store(e, Og + idx);
    }
  }

  if (t == 0) {
    float tot = 0.f;
#pragma unroll
    for (int w = 0; w < 4; ++w) tot += wsumX[w] + wsumS[w];
    atomicAdd(loss_out, tot * lscale);
  }
}

extern "C" void kernel_launch(void* const* d_in, const int* in_sizes, int n_in,
                              void* d_out, int out_size, void* d_ws, size_t ws_size,
                              hipStream_t stream) {
  const float* X = (const float*)d_in[0];
  const float* CB = (const float*)d_in[1];
  float* out = (float*)d_out;

  const int ND = in_sizes[0];      // 16*4096*256 = 16777216
  const int K = in_sizes[1] / DD;  // 1024
  const int N = ND / DD;           // 65536

  unsigned short* ws_nrmh = (unsigned short*)d_ws;                // K bf16 (2 KiB)
  unsigned short* ws_cb = (unsigned short*)((char*)d_ws + 2048);  // K*D bf16
  float* loss_out = out + (size_t)ND;

  vq_prep<<<K / 4, 256, 0, stream>>>(CB, ws_nrmh, ws_cb, loss_out);

  const float lscale = 1.25f / (float)ND;
  vq_main<<<N / BM, NTHR, 0, stream>>>(X, CB, ws_nrmh, ws_cb, out, loss_out, lscale);
}

// Round 7
// 64.578 us; speedup vs baseline: 2.9619x; 1.0297x over previous
//
#include <hip/hip_runtime.h>

typedef __attribute__((ext_vector_type(8))) short bf16x8;
typedef __attribute__((ext_vector_type(4))) float f32x4;
typedef __attribute__((ext_vector_type(4))) unsigned short u16x4;

static __device__ __forceinline__ unsigned short f2bf_rne(float f) {
  unsigned u = __float_as_uint(f);
  u += 0x7FFFu + ((u >> 16) & 1u);
  return (unsigned short)(u >> 16);
}
static __device__ __forceinline__ float bf2f(unsigned short h) {
  return __uint_as_float(((unsigned)h) << 16);
}
static __device__ __forceinline__ unsigned umin2(unsigned a, unsigned b) { return a < b ? a : b; }

// ---------------- Kernel 1: prep ----------------
// codebook fp32 -> bf16 (ws), nrmh = bf16(sum(bf16(e)^2)) (consistent with MFMA dot),
// zero the loss accumulator at d_out[N*D].
__global__ void vq_prep(const float* __restrict__ cb,
                        unsigned short* __restrict__ nrmh,
                        unsigned short* __restrict__ cbh,
                        float* __restrict__ loss_out) {
  if (blockIdx.x == 0 && threadIdx.x == 0) *loss_out = 0.0f;
  const int lane = threadIdx.x & 63;
  const int code = (blockIdx.x * blockDim.x + threadIdx.x) >> 6;  // one wave per code
  const f32x4 v = ((const f32x4*)(cb + (long)code * 256))[lane];
  u16x4 h;
  float n = 0.f;
#pragma unroll
  for (int j = 0; j < 4; ++j) {
    unsigned short b = f2bf_rne(v[j]);
    h[j] = (unsigned short)b;
    float bf = bf2f(b);
    n = __builtin_fmaf(bf, bf, n);
  }
  ((u16x4*)(cbh + (long)code * 256))[lane] = h;
#pragma unroll
  for (int m = 1; m < 64; m <<= 1) n += __shfl_xor(n, m);
  if (lane == 0) nrmh[code] = f2bf_rne(n);
}

// ---------------- Kernel 2: main ----------------
#define BM 128    // rows per block
#define DD 256    // embedding dim
#define NTHR 256  // 4 waves, 32 rows per wave (M_w=32)
#define CT 64     // codes per subtile (32 KiB bf16)
#define NSUB 16   // 1024 / CT

__global__ __launch_bounds__(NTHR, 2)
void vq_main(const float* __restrict__ X,
             const float* __restrict__ CB,
             const unsigned short* __restrict__ nrmh_g,
             const unsigned short* __restrict__ cbh,
             float* __restrict__ out,
             float* __restrict__ loss_out,
             float lscale) {
  // E double buffer: 2 x (64 codes x 256 dims) bf16 = 64 KiB, swizzled
  __shared__ __attribute__((aligned(16))) unsigned short Eb[2 * CT * DD];
  __shared__ __attribute__((aligned(16))) unsigned short nrmLds[1024];  // 2 KiB
  __shared__ float wsumX[4];
  __shared__ float wsumS[4];

  const int t = threadIdx.x;
  const int lane = t & 63;
  const int wave = t >> 6;  // 0..3 : owns rows 32*wave .. 32*wave+31
  const int lo16 = lane & 15;
  const int hi = lane >> 4;
  const long rowBase = (long)blockIdx.x * BM;

  // ---- staging: subtile = 32 KiB; 4 waves x 8 chunks x (64 lanes x 16B).
  // LDS dest linear (wave-uniform base + lane*16); global SOURCE pre-swizzled with the
  // involution o ^= ((o>>9)&7)<<4 so swizzled ds_reads decode it (rule #21).
  const char* cbB = (const char*)cbh;
  char* ebBase = (char*)Eb;
#define STAGE_E(ST, BUF)                                                                      \
  {                                                                                           \
    _Pragma("unroll") for (int c = 0; c < 8; ++c) {                                           \
      unsigned o = (unsigned)(wave * 8192 + c * 1024 + lane * 16);                            \
      unsigned src = o ^ (((o >> 9) & 7u) << 4);                                              \
      __builtin_amdgcn_global_load_lds(                                                       \
          (const __attribute__((address_space(1))) void*)(cbB + (unsigned)(ST)*32768u + src), \
          (__attribute__((address_space(3))) void*)(ebBase + (BUF)*32768 + wave * 8192 + c * 1024), \
          16, 0, 0);                                                                          \
    }                                                                                         \
  }

  // issue subtile-0 DMA first so it overlaps the A preload
  STAGE_E(0, 0);

  // ---- stage all 1024 bf16 norms into LDS (512 u32 by 256 threads) ----
  ((unsigned*)nrmLds)[t] = ((const unsigned*)nrmh_g)[t];
  ((unsigned*)nrmLds)[t + 256] = ((const unsigned*)nrmh_g)[t + 256];

  // ---- A preload: 32 rows/wave (2 sets of 16), fp32 global (nt) -> bf16 regs; ||x||^2 ----
  float xn = 0.f;
  bf16x8 a[2][8];
#pragma unroll
  for (int s = 0; s < 2; ++s) {
    const f32x4* xr = (const f32x4*)(X + (rowBase + wave * 32 + s * 16 + lo16) * DD);
#pragma unroll
    for (int ks = 0; ks < 8; ++ks) {
      f32x4 v0 = __builtin_nontemporal_load(xr + ks * 8 + hi * 2);
      f32x4 v1 = __builtin_nontemporal_load(xr + ks * 8 + hi * 2 + 1);
      bf16x8 aa;
#pragma unroll
      for (int j = 0; j < 4; ++j) {
        xn = __builtin_fmaf(v0[j], v0[j], xn);
        aa[j] = (short)f2bf_rne(v0[j]);
      }
#pragma unroll
      for (int j = 0; j < 4; ++j) {
        xn = __builtin_fmaf(v1[j], v1[j], xn);
        aa[4 + j] = (short)f2bf_rne(v1[j]);
      }
      a[s][ks] = aa;
    }
  }
  __syncthreads();  // nrmLds visible to all (A-load waits already drained vmcnt for STAGE too)

  unsigned best[2][4];
#pragma unroll
  for (int s = 0; s < 2; ++s)
#pragma unroll
    for (int r = 0; r < 4; ++r) best[s][r] = 0xFFFFFFFFu;

  const unsigned swzl = (unsigned)((lo16 & 7) << 4);
  const unsigned hi16 = (unsigned)(hi * 16);
  unsigned nbase[4];
#pragma unroll
  for (int n = 0; n < 4; ++n) nbase[n] = (unsigned)((lo16 + n * 16) * 512);

#pragma unroll 2
  for (int st = 0; st < NSUB; ++st) {
    if (st + 1 < NSUB) {
      STAGE_E(st + 1, (st + 1) & 1);
      asm volatile("s_waitcnt vmcnt(8)" ::: "memory");  // subtile st's 8 chunks landed; st+1 in flight
    } else {
      asm volatile("s_waitcnt vmcnt(0)" ::: "memory");
    }
    __builtin_amdgcn_s_barrier();       // all waves' stage(st) writes visible
    __builtin_amdgcn_sched_barrier(0);  // pin: no ds_read hoists above (rule #18)

    const char* eb = ebBase + (st & 1) * 32768;
    f32x4 acc[2][4];
#pragma unroll
    for (int s = 0; s < 2; ++s)
#pragma unroll
      for (int n = 0; n < 4; ++n) {
        f32x4 z = {0.f, 0.f, 0.f, 0.f};
        acc[s][n] = z;
      }
    __builtin_amdgcn_s_setprio(1);
#pragma unroll
    for (int ks = 0; ks < 8; ++ks) {
      unsigned kx = ((unsigned)(ks * 64) + hi16) ^ swzl;  // XOR-compose swizzle (bits 4-6 overlap)
      bf16x8 b0 = *(const bf16x8*)(eb + nbase[0] + kx);
      bf16x8 b1 = *(const bf16x8*)(eb + nbase[1] + kx);
      bf16x8 b2 = *(const bf16x8*)(eb + nbase[2] + kx);
      bf16x8 b3 = *(const bf16x8*)(eb + nbase[3] + kx);
      acc[0][0] = __builtin_amdgcn_mfma_f32_16x16x32_bf16(a[0][ks], b0, acc[0][0], 0, 0, 0);
      acc[1][0] = __builtin_amdgcn_mfma_f32_16x16x32_bf16(a[1][ks], b0, acc[1][0], 0, 0, 0);
      acc[0][1] = __builtin_amdgcn_mfma_f32_16x16x32_bf16(a[0][ks], b1, acc[0][1], 0, 0, 0);
      acc[1][1] = __builtin_amdgcn_mfma_f32_16x16x32_bf16(a[1][ks], b1, acc[1][1], 0, 0, 0);
      acc[0][2] = __builtin_amdgcn_mfma_f32_16x16x32_bf16(a[0][ks], b2, acc[0][2], 0, 0, 0);
      acc[1][2] = __builtin_amdgcn_mfma_f32_16x16x32_bf16(a[1][ks], b2, acc[1][2], 0, 0, 0);
      acc[0][3] = __builtin_amdgcn_mfma_f32_16x16x32_bf16(a[0][ks], b3, acc[0][3], 0, 0, 0);
      acc[1][3] = __builtin_amdgcn_mfma_f32_16x16x32_bf16(a[1][ks], b3, acc[1][3], 0, 0, 0);
    }
    __builtin_amdgcn_s_setprio(0);

    // score = ||e||^2 - 2 x.e; pack (monotone(score) & ~1023) | code; running min
#pragma unroll
    for (int n = 0; n < 4; ++n) {
      float nf = bf2f(nrmLds[st * 64 + n * 16 + lo16]);
      unsigned code = (unsigned)(st * 64 + n * 16 + lo16);
#pragma unroll
      for (int s = 0; s < 2; ++s)
#pragma unroll
        for (int r = 0; r < 4; ++r) {
          float sv = __builtin_fmaf(-2.0f, acc[s][n][r], nf);
          unsigned u = __float_as_uint(sv);
          u = ((int)u < 0) ? ~u : (u | 0x80000000u);
          best[s][r] = umin2(best[s][r], (u & 0xFFFFFC00u) | code);
        }
    }

    __builtin_amdgcn_sched_barrier(0);  // keep this subtile's reads/MFMA above barrier B
    __builtin_amdgcn_s_barrier();       // slot st&1 free for stage(st+2)
  }

  // ---- butterfly over the 16 code-lanes: per-row global min ----
#pragma unroll
  for (int s = 0; s < 2; ++s)
#pragma unroll
    for (int r = 0; r < 4; ++r) {
#pragma unroll
      for (int msk = 1; msk < 16; msk <<= 1)
        best[s][r] = umin2(best[s][r], (unsigned)__shfl_xor((int)best[s][r], msk));
    }

  // ---- wave-reduce ||x||^2 partials ----
#pragma unroll
  for (int msk = 1; msk < 64; msk <<= 1) xn += __shfl_xor(xn, msk);
  if (lane == 0) wsumX[wave] = xn;

  __syncthreads();  // Eb free; all vmcnt drained (last iter waited vmcnt(0))
  unsigned* mg = (unsigned*)Eb;  // [128] final keys
  unsigned* idxArr = mg + BM;    // [128] decoded indices
  if (lo16 == 0) {
#pragma unroll
    for (int s = 0; s < 2; ++s)
#pragma unroll
      for (int r = 0; r < 4; ++r) {
        // C/D layout: row_in_16 = (lane>>4)*4 + r
        mg[wave * 32 + s * 16 + hi * 4 + r] = best[s][r];
      }
  }
  __syncthreads();
  float sc = 0.f;
  if (t < BM) {
    unsigned e = mg[t];
    idxArr[t] = e & 1023u;
    // decode score (midpoint of truncated key) for the analytic loss
    unsigned um = (e & 0xFFFFFC00u) | 512u;
    sc = (um & 0x80000000u) ? __uint_as_float(um & 0x7FFFFFFFu) : __uint_as_float(~um);
  }
#pragma unroll
  for (int msk = 1; msk < 64; msk <<= 1) sc += __shfl_xor(sc, msk);
  if (lane == 0) wsumS[wave] = sc;
  __syncthreads();

  // ---- gather fp32 codebook rows -> output (non-temporal store) ----
  {
    const f32x4* CBv = (const f32x4*)CB;
    f32x4* Og = (f32x4*)(out + rowBase * DD);
#pragma unroll 4
    for (int i = 0; i < 32; ++i) {
      int idx = t + NTHR * i;
      int row = idx >> 6, d4 = idx & 63;
      int code = (int)idxArr[row];
      f32x4 e = CBv[code * 64 + d4];
      __builtin_nontemporal_store(e, Og + idx);
    }
  }

  if (t == 0) {
    float tot = 0.f;
#pragma unroll
    for (int w = 0; w < 4; ++w) tot += wsumX[w] + wsumS[w];
    atomicAdd(loss_out, tot * lscale);
  }
}

extern "C" void kernel_launch(void* const* d_in, const int* in_sizes, int n_in,
                              void* d_out, int out_size, void* d_ws, size_t ws_size,
                              hipStream_t stream) {
  const float* X = (const float*)d_in[0];
  const float* CB = (const float*)d_in[1];
  float* out = (float*)d_out;

  const int ND = in_sizes[0];      // 16*4096*256 = 16777216
  const int K = in_sizes[1] / DD;  // 1024
  const int N = ND / DD;           // 65536

  unsigned short* ws_nrmh = (unsigned short*)d_ws;                // K bf16 (2 KiB)
  unsigned short* ws_cb = (unsigned short*)((char*)d_ws + 2048);  // K*D bf16
  float* loss_out = out + (size_t)ND;

  vq_prep<<<K / 4, 256, 0, stream>>>(CB, ws_nrmh, ws_cb, loss_out);

  const float lscale = 1.25f / (float)ND;
  vq_main<<<N / BM, NTHR, 0, stream>>>(X, CB, ws_nrmh, ws_cb, out, loss_out, lscale);
}

// Round 8
// 56.946 us; speedup vs baseline: 3.3589x; 1.1340x over previous
//
#include <hip/hip_runtime.h>

typedef __attribute__((ext_vector_type(4))) float f32x4;
typedef __attribute__((ext_vector_type(2))) long i64x2;

#define SCALE 262144.0f        // 2^18 codebook prescale
#define NEG2S -524288.0f       // -2 * SCALE
#define INV_S2 1.4551915228366852e-11f  // 2^-36, exact

static __device__ __forceinline__ unsigned umin2(unsigned a, unsigned b) { return a < b ? a : b; }

// exact e4m3fn decode (bias 7, 3-bit mantissa, denormals at 2^-9)
static __device__ __forceinline__ float dec_e4m3(unsigned b) {
  int e = (b >> 3) & 15, m = b & 7;
  float v = e ? ldexpf((float)(8 + m), e - 10) : ldexpf((float)m, -9);
  return (b & 0x80) ? -v : v;
}

// ---------------- Kernel 1: prep ----------------
// codebook fp32 -> (x SCALE) -> fp8 e4m3, stored PERMUTED: for k = ks*32+hi*8+j,
// byte position = hi*64 + ks*8 + j  (so ds_read_b128 covers 2 k-steps per fragment).
// norms[code] = sum(dec(fp8)^2) fp32 (exact, consistent with MFMA dot).
__global__ void vq_prep(const float* __restrict__ cb,
                        float* __restrict__ norms,
                        unsigned char* __restrict__ cbh,
                        float* __restrict__ loss_out) {
  if (blockIdx.x == 0 && threadIdx.x == 0) *loss_out = 0.0f;
  const int lane = threadIdx.x & 63;
  const int code = (blockIdx.x * blockDim.x + threadIdx.x) >> 6;  // one wave per code
  const f32x4 v = ((const f32x4*)(cb + (long)code * 256))[lane];  // k = 4*lane .. +3
  unsigned w = __builtin_amdgcn_cvt_pk_fp8_f32(v[0] * SCALE, v[1] * SCALE, 0, false);
  w = __builtin_amdgcn_cvt_pk_fp8_f32(v[2] * SCALE, v[3] * SCALE, w, true);
  float n = 0.f;
#pragma unroll
  for (int j = 0; j < 4; ++j) {
    float d = dec_e4m3((w >> (8 * j)) & 0xFFu);
    n = __builtin_fmaf(d, d, n);
  }
  // k0 = 4*lane: ks = lane>>3, hi = (lane>>1)&3, j0 = (lane&1)*4
  const int newpos = ((lane >> 1) & 3) * 64 + (lane >> 3) * 8 + (lane & 1) * 4;
  *(unsigned*)(cbh + (long)code * 256 + newpos) = w;
#pragma unroll
  for (int m = 1; m < 64; m <<= 1) n += __shfl_xor(n, m);
  if (lane == 0) norms[code] = n;
}

// ---------------- Kernel 2: main ----------------
#define BM 128    // rows per block
#define DD 256    // embedding dim
#define NTHR 512  // 8 waves, 16 rows per wave
#define CT 64     // codes per subtile (16 KiB fp8)
#define NSUB 16   // 1024 / CT

__global__ __launch_bounds__(NTHR, 4)
void vq_main(const float* __restrict__ X,
             const float* __restrict__ CB,
             const float* __restrict__ norms_g,
             const unsigned char* __restrict__ cbh,
             float* __restrict__ out,
             float* __restrict__ loss_out,
             float lscale) {
  // E double buffer: 2 x (64 codes x 256B fp8) = 32 KiB
  __shared__ __attribute__((aligned(16))) unsigned char Eb[2 * CT * DD];
  __shared__ __attribute__((aligned(16))) float nrmLds[1024];  // 4 KiB fp32
  __shared__ float wsumX[8];
  __shared__ float wsumS[8];

  const int t = threadIdx.x;
  const int lane = t & 63;
  const int wave = t >> 6;  // 0..7 : owns rows 16*wave .. 16*wave+15
  const int lo16 = lane & 15;
  const int hi = lane >> 4;
  const long rowBase = (long)blockIdx.x * BM;

  // ---- staging: subtile = 16 KiB; 8 waves x 2 chunks x (64 lanes x 16B).
  // LDS dest linear; global SOURCE pre-swizzled with involution o ^= ((o>>8)&7)<<4
  // (rows are 256B; swizzle bits 4-6 keep 16B DMA alignment).
  const char* cbB = (const char*)cbh;
  char* ebBase = (char*)Eb;
#define STAGE_E(ST, BUF)                                                                      \
  {                                                                                           \
    _Pragma("unroll") for (int c = 0; c < 2; ++c) {                                           \
      unsigned o = (unsigned)(wave * 2048 + c * 1024 + lane * 16);                            \
      unsigned src = o ^ ((((o >> 8) & 7u)) << 4);                                            \
      __builtin_amdgcn_global_load_lds(                                                       \
          (const __attribute__((address_space(1))) void*)(cbB + (unsigned)(ST)*16384u + src), \
          (__attribute__((address_space(3))) void*)(ebBase + (BUF)*16384 + wave * 2048 + c * 1024), \
          16, 0, 0);                                                                          \
    }                                                                                         \
  }

  STAGE_E(0, 0);  // overlap subtile-0 DMA with A preload

  // ---- stage norms (fp32) into LDS ----
  nrmLds[t] = norms_g[t];
  nrmLds[t + 512] = norms_g[t + 512];

  // ---- A preload: 16 rows/wave, fp32 global (nt) -> fp8 regs; accumulate ||x||^2 ----
  float xn = 0.f;
  long a[8];
  {
    const f32x4* xr = (const f32x4*)(X + (rowBase + wave * 16 + lo16) * DD);
#pragma unroll
    for (int ks = 0; ks < 8; ++ks) {
      f32x4 v0 = __builtin_nontemporal_load(xr + ks * 8 + hi * 2);
      f32x4 v1 = __builtin_nontemporal_load(xr + ks * 8 + hi * 2 + 1);
#pragma unroll
      for (int j = 0; j < 4; ++j) xn = __builtin_fmaf(v0[j], v0[j], xn);
#pragma unroll
      for (int j = 0; j < 4; ++j) xn = __builtin_fmaf(v1[j], v1[j], xn);
      unsigned w0 = __builtin_amdgcn_cvt_pk_fp8_f32(v0[0], v0[1], 0, false);
      w0 = __builtin_amdgcn_cvt_pk_fp8_f32(v0[2], v0[3], w0, true);
      unsigned w1 = __builtin_amdgcn_cvt_pk_fp8_f32(v1[0], v1[1], 0, false);
      w1 = __builtin_amdgcn_cvt_pk_fp8_f32(v1[2], v1[3], w1, true);
      a[ks] = (long)w0 | ((long)w1 << 32);
    }
  }
  __syncthreads();  // nrmLds visible

  unsigned best[4];
#pragma unroll
  for (int r = 0; r < 4; ++r) best[r] = 0xFFFFFFFFu;

  const unsigned swzl = (unsigned)((lo16 & 7) << 4);
  unsigned nbase[4];
#pragma unroll
  for (int n = 0; n < 4; ++n) nbase[n] = (unsigned)((n * 16 + lo16) * 256) ^ swzl;
  const unsigned hi64 = (unsigned)(hi * 64);

#pragma unroll 2
  for (int st = 0; st < NSUB; ++st) {
    if (st + 1 < NSUB) {
      STAGE_E(st + 1, (st + 1) & 1);
      asm volatile("s_waitcnt vmcnt(2)" ::: "memory");  // subtile st's 2 chunks landed
    } else {
      asm volatile("s_waitcnt vmcnt(0)" ::: "memory");
    }
    __builtin_amdgcn_s_barrier();       // stage(st) visible to all waves
    __builtin_amdgcn_sched_barrier(0);  // no ds_read hoists above (rule #18)

    const char* eb = ebBase + (st & 1) * 16384;
    f32x4 acc[4];
#pragma unroll
    for (int n = 0; n < 4; ++n) {
      f32x4 z = {0.f, 0.f, 0.f, 0.f};
      acc[n] = z;
    }
    __builtin_amdgcn_s_setprio(1);
#pragma unroll
    for (int kp = 0; kp < 4; ++kp) {
      const unsigned koff = hi64 + (unsigned)(kp * 16);  // bits 4-7; XOR vs swizzled base
      i64x2 b0 = *(const i64x2*)(eb + (nbase[0] ^ koff));
      i64x2 b1 = *(const i64x2*)(eb + (nbase[1] ^ koff));
      i64x2 b2 = *(const i64x2*)(eb + (nbase[2] ^ koff));
      i64x2 b3 = *(const i64x2*)(eb + (nbase[3] ^ koff));
      acc[0] = __builtin_amdgcn_mfma_f32_16x16x32_fp8_fp8(a[2 * kp], b0.x, acc[0], 0, 0, 0);
      acc[1] = __builtin_amdgcn_mfma_f32_16x16x32_fp8_fp8(a[2 * kp], b1.x, acc[1], 0, 0, 0);
      acc[2] = __builtin_amdgcn_mfma_f32_16x16x32_fp8_fp8(a[2 * kp], b2.x, acc[2], 0, 0, 0);
      acc[3] = __builtin_amdgcn_mfma_f32_16x16x32_fp8_fp8(a[2 * kp], b3.x, acc[3], 0, 0, 0);
      acc[0] = __builtin_amdgcn_mfma_f32_16x16x32_fp8_fp8(a[2 * kp + 1], b0.y, acc[0], 0, 0, 0);
      acc[1] = __builtin_amdgcn_mfma_f32_16x16x32_fp8_fp8(a[2 * kp + 1], b1.y, acc[1], 0, 0, 0);
      acc[2] = __builtin_amdgcn_mfma_f32_16x16x32_fp8_fp8(a[2 * kp + 1], b2.y, acc[2], 0, 0, 0);
      acc[3] = __builtin_amdgcn_mfma_f32_16x16x32_fp8_fp8(a[2 * kp + 1], b3.y, acc[3], 0, 0, 0);
    }
    __builtin_amdgcn_s_setprio(0);

    // score'' = ||e''||^2 - 2*S*(x.e''); pack (monotone & ~1023) | code; running min
#pragma unroll
    for (int n = 0; n < 4; ++n) {
      float nf = nrmLds[st * 64 + n * 16 + lo16];
      unsigned code = (unsigned)(st * 64 + n * 16 + lo16);
#pragma unroll
      for (int r = 0; r < 4; ++r) {
        float sv = __builtin_fmaf(NEG2S, acc[n][r], nf);
        unsigned u = __float_as_uint(sv);
        u = ((int)u < 0) ? ~u : (u | 0x80000000u);
        best[r] = umin2(best[r], (u & 0xFFFFFC00u) | code);
      }
    }

    __builtin_amdgcn_sched_barrier(0);  // keep this subtile's reads/MFMA above barrier B
    __builtin_amdgcn_s_barrier();       // slot st&1 free for stage(st+2)
  }

  // ---- butterfly over the 16 code-lanes (lo16): per-row global min ----
#pragma unroll
  for (int r = 0; r < 4; ++r) {
#pragma unroll
    for (int msk = 1; msk < 16; msk <<= 1)
      best[r] = umin2(best[r], (unsigned)__shfl_xor((int)best[r], msk));
  }

  // ---- wave-reduce ||x||^2 partials ----
#pragma unroll
  for (int msk = 1; msk < 64; msk <<= 1) xn += __shfl_xor(xn, msk);
  if (lane == 0) wsumX[wave] = xn;

  __syncthreads();  // Eb free (vmcnt fully drained on last iter)
  unsigned* mg = (unsigned*)Eb;  // [128] final keys
  unsigned* idxArr = mg + BM;    // [128] decoded indices
  if (lo16 == 0) {
#pragma unroll
    for (int r = 0; r < 4; ++r) {
      // C/D layout: row_in_16 = (lane>>4)*4 + r
      mg[wave * 16 + hi * 4 + r] = best[r];
    }
  }
  __syncthreads();
  float sc = 0.f;
  if (t < BM) {
    unsigned e = mg[t];
    idxArr[t] = e & 1023u;
    // decode score'' (midpoint of truncated key), rescale to real units
    unsigned um = (e & 0xFFFFFC00u) | 512u;
    float sr = (um & 0x80000000u) ? __uint_as_float(um & 0x7FFFFFFFu) : __uint_as_float(~um);
    sc = sr * INV_S2;
  }
#pragma unroll
  for (int msk = 1; msk < 64; msk <<= 1) sc += __shfl_xor(sc, msk);
  if (lane == 0) wsumS[wave] = sc;
  __syncthreads();

  // ---- gather fp32 codebook rows -> output (non-temporal store) ----
  {
    const f32x4* CBv = (const f32x4*)CB;
    f32x4* Og = (f32x4*)(out + rowBase * DD);
#pragma unroll 4
    for (int i = 0; i < 16; ++i) {
      int idx = t + NTHR * i;
      int row = idx >> 6, d4 = idx & 63;
      int code = (int)idxArr[row];
      f32x4 e = CBv[code * 64 + d4];
      __builtin_nontemporal_store(e, Og + idx);
    }
  }

  if (t == 0) {
    float tot = 0.f;
#pragma unroll
    for (int w = 0; w < 8; ++w) tot += wsumX[w] + wsumS[w];
    atomicAdd(loss_out, tot * lscale);
  }
}

extern "C" void kernel_launch(void* const* d_in, const int* in_sizes, int n_in,
                              void* d_out, int out_size, void* d_ws, size_t ws_size,
                              hipStream_t stream) {
  const float* X = (const float*)d_in[0];
  const float* CB = (const float*)d_in[1];
  float* out = (float*)d_out;

  const int ND = in_sizes[0];      // 16*4096*256 = 16777216
  const int K = in_sizes[1] / DD;  // 1024
  const int N = ND / DD;           // 65536

  float* ws_norms = (float*)d_ws;                                 // K fp32 (4 KiB)
  unsigned char* ws_cb = (unsigned char*)((char*)d_ws + 4096);    // K*D fp8 (permuted)
  float* loss_out = out + (size_t)ND;

  vq_prep<<<K / 4, 256, 0, stream>>>(CB, ws_norms, ws_cb, loss_out);

  const float lscale = 1.25f / (float)ND;
  vq_main<<<N / BM, NTHR, 0, stream>>>(X, CB, ws_norms, ws_cb, out, loss_out, lscale);
}